// Round 12
// baseline (881.793 us; speedup 1.0000x reference)
//
#include <hip/hip_runtime.h>
#include <math.h>

#define NB 16
#define INW 256
#define GN 100
#define NV (GN*GN)          // 10000
#define NPROB (NB*2)        // 32
#define K_TOP 20
#define HSZ 8192
#define KB 64               // positional buckets per problem
#define SNAPN 8             // snapshots (every 8 buckets)
#define RCAP 3072           // max regions per problem
#define MYCAP 128           // max edges per bucket
#define LISTCAP 3072        // max bars per problem
#define RBLK 625            // resize blocks (NB*NV/256)

// ws layout (end ~5.64 MB)
#define OFF_RES   0               // NB*NV f32 = 640000   (dead after hash_k)
#define OFF_LAB   640000          // NPROB*NV u16 (spn parent; dead after chase_k... kept til hash? no: flab used)
#define OFF_DENSE 1280000         // NPROB*NV u16         (dead after hash_k)
#define OFF_STATE 0               // overlay: NPROB*SNAPN*RCAP u16 = 1572864 (written by sortcc, after hash)
#define OFF_ROOTV 1920000         // NPROB*RCAP u16 = 196608
#define OFF_D2B   2116608         // NPROB*RCAP f32 = 393216
#define OFF_TAB   2509824         // NPROB*HSZ u64 = 2097152 (hash table -> sorted edges)
#define OFF_ECNT  4606976         // NPROB u32
#define OFF_RCNT  4607104         // NPROB u32
#define OFF_LCNT  4607232         // NPROB u32
#define OFF_LIST  4607360         // NPROB*LISTCAP f32 = 393216
#define OFF_PART  5000576         // NPROB f32 = 128
#define OFF_FLAB  5000704         // NPROB*NV u16 = 640000 (final labels)

__device__ __forceinline__ int imin(int a, int b){ return a < b ? a : b; }
__device__ __forceinline__ int imax(int a, int b){ return a > b ? a : b; }

__device__ __forceinline__ unsigned mono32(float f){
  unsigned b = __float_as_uint(f);
  return (b & 0x80000000u) ? ~b : (b | 0x80000000u);
}
__device__ __forceinline__ float unmono(unsigned m){
  unsigned b = (m & 0x80000000u) ? (m ^ 0x80000000u) : ~m;
  return __uint_as_float(b);
}

__device__ __forceinline__ unsigned uf_find(volatile unsigned* par, unsigned x){
  unsigned p = par[x];
  while (p != x) {
    unsigned g = par[p];
    if (g != p) par[x] = g;
    x = g;
    p = par[x];
  }
  return x;
}
__device__ __forceinline__ void uf_union(volatile unsigned* vpar, unsigned* par,
                                         unsigned a, unsigned b){
  while (1) {
    unsigned ra = uf_find(vpar, a);
    unsigned rb = uf_find(vpar, b);
    if (ra == rb) break;
    unsigned lo = (ra < rb) ? ra : rb, hi = (ra < rb) ? rb : ra;
    if (atomicCAS(&par[hi], hi, lo) == hi) break;
    a = lo; b = hi;
  }
}

__device__ __forceinline__ void cub_w(int i, int& j0, float w[4]) {
  double inv = (double)INW / (double)GN;
  double sf  = ((double)i + 0.5) * inv - 0.5;
  j0 = (int)floor(sf) - 1;
  double wd[4]; double s = 0.0;
  #pragma unroll
  for (int k = 0; k < 4; ++k) {
    int j = j0 + k;
    double t = fabs(sf - (double)j);
    double v;
    if (t < 1.0)      v = ((1.5*t - 2.5)*t)*t + 1.0;
    else if (t < 2.0) v = ((-0.5*t + 2.5)*t - 4.0)*t + 2.0;
    else              v = 0.0;
    if (j < 0 || j >= INW) v = 0.0;
    wd[k] = v; s += v;
  }
  #pragma unroll
  for (int k = 0; k < 4; ++k) w[k] = (float)(wd[k] / s);
}

// ---------------------------------------------------------------------------
// Kernel 1: bicubic resize (blocks 0..624) + per-problem init (blocks 625..656)
// ---------------------------------------------------------------------------
__global__ __launch_bounds__(256) void resize_init_k(const float* __restrict__ in, float* ws) {
  int tid = threadIdx.x;
  if (blockIdx.x >= RBLK) {
    int p = blockIdx.x - RBLK;                 // 0..31
    unsigned long long* tab = (unsigned long long*)((char*)ws + OFF_TAB) + (size_t)p * HSZ;
    for (int i = tid; i < HSZ; i += 256) tab[i] = 0ull;
    if (tid == 0) {
      ((unsigned*)((char*)ws + OFF_ECNT))[p] = 0u;
      ((unsigned*)((char*)ws + OFF_RCNT))[p] = 0u;
      ((unsigned*)((char*)ws + OFF_LCNT))[p] = 0u;
    }
    return;
  }
  float* outp = (float*)((char*)ws + OFF_RES);
  int idx = blockIdx.x * 256 + tid;
  if (idx >= NB * NV) return;
  int b = idx / NV; int rem = idx - b * NV;
  int i = rem / GN; int j = rem - i * GN;
  const float* img = in + (size_t)b * INW * INW;
  int r0, c0; float wr[4], wc[4];
  cub_w(i, r0, wr);
  cub_w(j, c0, wc);
  float acc = 0.f;
  #pragma unroll
  for (int kr = 0; kr < 4; ++kr) {
    int rr = imin(imax(r0 + kr, 0), INW - 1);
    const float* row = img + rr * INW;
    int c0c = imin(imax(c0 + 0, 0), INW - 1);
    int c1c = imin(imax(c0 + 1, 0), INW - 1);
    int c2c = imin(imax(c0 + 2, 0), INW - 1);
    int c3c = imin(imax(c0 + 3, 0), INW - 1);
    float rs = wc[0]*row[c0c] + wc[1]*row[c1c] + wc[2]*row[c2c] + wc[3]*row[c3c];
    acc += wr[kr] * rs;
  }
  outp[idx] = acc;
}

// ---------------------------------------------------------------------------
// Kernel 2: steepest-earlier-neighbor (grid-wide parallel, one thread/vertex)
// ---------------------------------------------------------------------------
__global__ __launch_bounds__(256) void spn_k(float* ws) {
  int idx = blockIdx.x * 256 + threadIdx.x;
  if (idx >= NPROB * NV) return;
  int p = idx / NV, v = idx - p * NV;
  int samp = p >> 1, neg = p & 1;
  const float* res = (const float*)((const char*)ws + OFF_RES) + samp * NV;
  unsigned short* glab = (unsigned short*)((char*)ws + OFF_LAB) + (size_t)p * NV;
  float sgn = neg ? -1.f : 1.f;
  const int nd = neg ? 4 : 6;
  int r = v / GN, c = v - r * GN;
  unsigned long long best = ((unsigned long long)mono32(sgn * res[v]) << 32) | (unsigned)~(unsigned)v;
  unsigned bi = (unsigned)v;
  bool cb[6] = { c < GN-1, c > 0, r < GN-1, r > 0,
                 (r < GN-1) && (c < GN-1), (r > 0) && (c > 0) };
  int  off[6] = { 1, -1, GN, -GN, GN+1, -(GN+1) };
  #pragma unroll
  for (int d = 0; d < 6; ++d) {
    if (d < nd && cb[d]) {
      unsigned y = (unsigned)(v + off[d]);
      unsigned long long o = ((unsigned long long)mono32(sgn * res[y]) << 32) | (unsigned)~y;
      if (o > best) { best = o; bi = y; }
    }
  }
  glab[v] = (unsigned short)bi;
}

// ---------------------------------------------------------------------------
// Kernel 3: chase to root (path-halving in global, ancestor-safe under races
// and staleness), write final label to flab, compact roots via atomicAdd.
// ---------------------------------------------------------------------------
__global__ __launch_bounds__(256) void chase_k(float* ws) {
  int idx = blockIdx.x * 256 + threadIdx.x;
  if (idx >= NPROB * NV) return;
  int p = idx / NV, v = idx - p * NV;
  int samp = p >> 1, neg = p & 1;
  const float* res = (const float*)((const char*)ws + OFF_RES) + samp * NV;
  volatile unsigned short* L = (unsigned short*)((char*)ws + OFF_LAB) + (size_t)p * NV;
  unsigned short* flab = (unsigned short*)((char*)ws + OFF_FLAB) + (size_t)p * NV;
  unsigned short* rootv = (unsigned short*)((char*)ws + OFF_ROOTV) + (size_t)p * RCAP;
  unsigned* rcnt = (unsigned*)((char*)ws + OFF_RCNT);
  unsigned x = (unsigned)v;
  unsigned px = L[x];
  while (px != x) {
    unsigned g = L[px];
    L[x] = (unsigned short)g;      // halving: g is an ancestor of x — always safe
    x = g;
    px = L[x];
  }
  flab[v] = (unsigned short)x;     // exclusively owned write
  if (x == (unsigned)v) {          // v is a root (static property)
    unsigned i = atomicAdd(&rcnt[p], 1u);
    if (i < RCAP) rootv[i] = (unsigned short)v;
  }
  (void)res; (void)neg;
}

// ---------------------------------------------------------------------------
// Kernel 4: rank roots desc (elder order) -> dense ids + birth table.
// 16 slices per problem; ords recomputed from rootv + res.
// ---------------------------------------------------------------------------
__global__ __launch_bounds__(256) void rank_root_k(float* ws) {
  __shared__ unsigned long long ro[RCAP];
  __shared__ unsigned short rv_sh[RCAP];
  int p = blockIdx.x / 16, sl = blockIdx.x % 16, tid = threadIdx.x;
  int samp = p >> 1, neg = p & 1;
  const float* res = (const float*)((const char*)ws + OFF_RES) + samp * NV;
  const unsigned short* rootv = (const unsigned short*)((const char*)ws + OFF_ROOTV) + (size_t)p * RCAP;
  unsigned short* dense = (unsigned short*)((char*)ws + OFF_DENSE) + (size_t)p * NV;
  float* d2b = (float*)((char*)ws + OFF_D2B) + (size_t)p * RCAP;
  const unsigned* rcnt = (const unsigned*)((const char*)ws + OFF_RCNT);
  unsigned R = rcnt[p]; if (R > RCAP) R = RCAP;
  float sgn = neg ? -1.f : 1.f;
  for (unsigned i = tid; i < R; i += 256) {
    unsigned v = rootv[i];
    ro[i] = ((unsigned long long)mono32(sgn * res[v]) << 32) | (unsigned)~v;
    rv_sh[i] = (unsigned short)v;
  }
  __syncthreads();
  unsigned RS = (R + 15) / 16;
  unsigned lo = sl * RS, hi = lo + RS; if (hi > R) hi = R;
  for (unsigned i = lo + tid; i < hi; i += 256) {
    unsigned long long oi = ro[i];
    unsigned r = 0;
    for (unsigned j = 0; j < R; ++j) r += (ro[j] > oi) ? 1u : 0u;
    dense[rv_sh[i]] = (unsigned short)r;
    d2b[r] = unmono((unsigned)(oi >> 32));
  }
}

// ---------------------------------------------------------------------------
// Kernel 5: boundary-edge dedup into GLOBAL u64 hash table (slot = ev<<32|pid,
// empty = 0; mono32 of finite floats is > 0). 8 vertex-slices per problem.
// ---------------------------------------------------------------------------
__global__ __launch_bounds__(256) void hash_k(float* ws) {
  int p = blockIdx.x >> 3, sl = blockIdx.x & 7, tid = threadIdx.x;
  int samp = p >> 1, neg = p & 1;
  const float* res = (const float*)((const char*)ws + OFF_RES) + samp * NV;
  const unsigned short* flab = (const unsigned short*)((const char*)ws + OFF_FLAB) + (size_t)p * NV;
  const unsigned short* gdense = (const unsigned short*)((const char*)ws + OFF_DENSE) + (size_t)p * NV;
  unsigned long long* tab = (unsigned long long*)((char*)ws + OFF_TAB) + (size_t)p * HSZ;
  float sgn = neg ? -1.f : 1.f;
  int v0 = sl * (NV / 8), v1 = v0 + (NV / 8);
  for (int v = v0 + tid; v < v1; v += 256) {
    int r = v / GN, c = v - r * GN;
    unsigned a = gdense[flab[v]];
    unsigned sv = mono32(sgn * res[v]);
    bool vb[3] = { c < GN-1, r < GN-1, (!neg) && (r < GN-1) && (c < GN-1) };
    int  vo[3] = { 1, GN, GN+1 };
    #pragma unroll
    for (int d = 0; d < 3; ++d) {
      if (vb[d]) {
        unsigned w = (unsigned)(v + vo[d]);
        unsigned b = gdense[flab[w]];
        if (a != b) {
          unsigned sw = mono32(sgn * res[w]);
          unsigned ev = (sv < sw) ? sv : sw;
          unsigned dlo = (a < b) ? a : b, dhi = (a < b) ? b : a;
          unsigned pid = (dlo << 16) | dhi;
          unsigned long long packed = ((unsigned long long)ev << 32) | pid;
          unsigned h = (pid * 2654435761u) >> 19;
          for (int t = 0; t < HSZ; ++t) {
            unsigned long long cur = tab[h];
            if (cur == 0ull) {
              unsigned long long old = atomicCAS(&tab[h], 0ull, packed);
              if (old == 0ull) break;
              cur = old;
            }
            if ((unsigned)cur == pid) { atomicMax(&tab[h], packed); break; }
            h = (h + 1) & (HSZ - 1);
          }
        }
      }
    }
  }
}

// ---------------------------------------------------------------------------
// Kernel 6: FUSED gather + in-LDS radix sort (desc by ev) + prefix-CC
// snapshots. One block/problem. Sorted edges written back over the table.
// ---------------------------------------------------------------------------
__global__ __launch_bounds__(256) void sortcc_k(float* ws) {
  __shared__ unsigned long long bufA[HSZ];    // 64KB
  __shared__ unsigned long long bufB[HSZ];    // 64KB (par after sort)
  __shared__ unsigned cnt[16 * 256];          // 16KB
  __shared__ unsigned tot[16];
  __shared__ unsigned mc_sh;
  int p = blockIdx.x, tid = threadIdx.x;
  unsigned long long* tab = (unsigned long long*)((char*)ws + OFF_TAB) + (size_t)p * HSZ;
  unsigned short* state = (unsigned short*)((char*)ws + OFF_STATE) + (size_t)p * SNAPN * RCAP;
  unsigned* ecnt = (unsigned*)((char*)ws + OFF_ECNT);
  const unsigned* rcnt = (const unsigned*)((const char*)ws + OFF_RCNT);
  unsigned R = rcnt[p]; if (R > RCAP) R = RCAP;
  if (tid == 0) mc_sh = 0;
  __syncthreads();
  for (int i = tid; i < HSZ; i += 256) {
    unsigned long long x = tab[i];
    if (x != 0ull) { unsigned k = atomicAdd(&mc_sh, 1u); bufA[k] = x; }
  }
  __syncthreads();
  unsigned E = mc_sh;
  unsigned chunk = (E + 255) >> 8;
  unsigned lo = tid * chunk; if (lo > E) lo = E;
  unsigned hi = lo + chunk; if (hi > E) hi = E;
  unsigned long long* src = bufA;
  unsigned long long* dst = bufB;
  for (int pass = 0; pass < 8; ++pass) {
    int shift = 32 + pass * 4;
    for (int d = tid; d < 16 * 256; d += 256) cnt[d] = 0;
    __syncthreads();
    for (unsigned i = lo; i < hi; ++i) {
      unsigned slot = 15u - ((unsigned)(src[i] >> shift) & 15u);
      cnt[slot * 256 + tid] += 1u;
    }
    __syncthreads();
    if (tid < 16) {
      unsigned s = 0;
      for (int t = 0; t < 256; ++t) {
        unsigned c = cnt[tid * 256 + t];
        cnt[tid * 256 + t] = s;
        s += c;
      }
      tot[tid] = s;
    }
    __syncthreads();
    if (tid == 0) {
      unsigned s = 0;
      for (int d = 0; d < 16; ++d) { unsigned c = tot[d]; tot[d] = s; s += c; }
    }
    __syncthreads();
    for (unsigned i = lo; i < hi; ++i) {
      unsigned long long x = src[i];
      unsigned slot = 15u - ((unsigned)(x >> shift) & 15u);
      unsigned off = cnt[slot * 256 + tid];
      cnt[slot * 256 + tid] = off + 1u;
      dst[tot[slot] + off] = x;
    }
    __syncthreads();
    unsigned long long* t2 = src; src = dst; dst = t2;
  }
  // 8 passes -> sorted data in bufA. Write back over the dead hash table.
  for (unsigned i = tid; i < E; i += 256) tab[i] = bufA[i];
  if (tid == 0) ecnt[p] = E;
  unsigned* par = (unsigned*)bufB;
  for (unsigned d = tid; d < R; d += 256) par[d] = d;
  __syncthreads();
  volatile unsigned* vpar = par;
  unsigned cp = (E + KB - 1) / KB;
  for (int s = 0; s < SNAPN; ++s) {
    for (unsigned d = tid; d < R; d += 256) {
      unsigned r = d;
      while (vpar[r] != r) r = vpar[r];
      par[d] = r;
      state[s * RCAP + d] = (unsigned short)r;
    }
    __syncthreads();
    unsigned e0 = (unsigned)s * 8u * cp; if (e0 > E) e0 = E;
    unsigned e1 = (unsigned)(s + 1) * 8u * cp; if (e1 > E) e1 = E;
    for (unsigned e = e0 + tid; e < e1; e += 256) {
      unsigned pid = (unsigned)bufA[e];
      uf_union(vpar, par, pid >> 16, pid & 0xffffu);
    }
    __syncthreads();
  }
}

// ---------------------------------------------------------------------------
// Kernel 7: bucketed Kruskal with speculative root hints (as R11).
// ---------------------------------------------------------------------------
__global__ __launch_bounds__(256) void kruskal_bucket_k(float* ws) {
  __shared__ unsigned par[RCAP];
  __shared__ unsigned hintR[MYCAP];
  __shared__ unsigned hintE[MYCAP];
  __shared__ float    hintB[MYCAP];
  __shared__ float    barbuf[MYCAP];
  __shared__ unsigned nb_sh, base_sh;
  int p = blockIdx.x / KB, bk = blockIdx.x % KB, tid = threadIdx.x;
  const unsigned long long* gedges = (const unsigned long long*)((const char*)ws + OFF_TAB) + (size_t)p * HSZ;
  const float* d2b = (const float*)((const char*)ws + OFF_D2B) + (size_t)p * RCAP;
  const unsigned short* state = (const unsigned short*)((const char*)ws + OFF_STATE) + (size_t)p * SNAPN * RCAP + (size_t)(bk >> 3) * RCAP;
  const unsigned* ecnt = (const unsigned*)((const char*)ws + OFF_ECNT);
  const unsigned* rcnt = (const unsigned*)((const char*)ws + OFF_RCNT);
  unsigned* lcnt = (unsigned*)((char*)ws + OFF_LCNT);
  float* glist = (float*)((char*)ws + OFF_LIST) + (size_t)p * LISTCAP;
  unsigned E = ecnt[p]; if (E > HSZ) E = HSZ;
  unsigned R = rcnt[p]; if (R > RCAP) R = RCAP;
  unsigned cp = (E + KB - 1) / KB;
  unsigned rep_lo = (unsigned)(bk & ~7) * cp; if (rep_lo > E) rep_lo = E;
  unsigned own_lo = (unsigned)bk * cp;        if (own_lo > E) own_lo = E;
  unsigned own_hi = own_lo + cp;              if (own_hi > E) own_hi = E;
  unsigned mc = own_hi - own_lo;
  for (unsigned d = tid; d < R; d += 256) par[d] = state[d];
  __syncthreads();
  volatile unsigned* vpar = par;
  for (unsigned e = rep_lo + tid; e < own_lo; e += 256) {
    unsigned pid = (unsigned)gedges[e];
    uf_union(vpar, par, pid >> 16, pid & 0xffffu);
  }
  __syncthreads();
  for (unsigned d = tid; d < R; d += 256) {
    unsigned r = d;
    while (vpar[r] != r) r = vpar[r];
    par[d] = r;
  }
  __syncthreads();
  if (tid < mc) {
    unsigned long long it = gedges[own_lo + tid];
    unsigned pid = (unsigned)it;
    unsigned ra = par[pid >> 16];
    unsigned rb = par[pid & 0xffffu];
    hintR[tid] = (ra << 16) | rb;
    hintE[tid] = (unsigned)(it >> 32);
    hintB[tid] = d2b[(ra > rb) ? ra : rb];
  }
  __syncthreads();
  if (tid >= 64) return;
  const int lane = tid;
  if (lane == 0) {
    unsigned nb = 0;
    for (unsigned e = 0; e < mc; ++e) {
      unsigned h = hintR[e];
      unsigned ra = h >> 16, rb = h & 0xffffu;
      if (ra == rb) continue;
      unsigned ca = ra, pa = par[ca];
      while (pa != ca) { unsigned ga = par[pa]; par[ca] = ga; ca = ga; pa = par[ca]; }
      unsigned cb = rb, pb = par[cb];
      while (pb != cb) { unsigned gb = par[pb]; par[cb] = gb; cb = gb; pb = par[cb]; }
      if (ca == cb) continue;
      unsigned win = (ca < cb) ? ca : cb;
      unsigned los = (ca < cb) ? cb : ca;
      float birth = (ca == ra && cb == rb) ? hintB[e] : d2b[los];
      barbuf[nb++] = birth - unmono(hintE[e]);
      par[los] = win;
    }
    nb_sh = nb;
  }
  __asm__ volatile("s_waitcnt lgkmcnt(0)" ::: "memory");
  __builtin_amdgcn_wave_barrier();
  if (lane == 0) base_sh = atomicAdd(&lcnt[p], nb_sh);
  __asm__ volatile("s_waitcnt vmcnt(0) lgkmcnt(0)" ::: "memory");
  __builtin_amdgcn_wave_barrier();
  unsigned nb = nb_sh, base = base_sh;
  for (unsigned i = lane; i < nb; i += 64) {
    unsigned idx = base + i;
    if (idx < LISTCAP) glist[idx] = barbuf[i];
  }
}

// ---------------------------------------------------------------------------
// Kernel 8: per-problem top-20 over compact bar list -> partial[p]
// ---------------------------------------------------------------------------
__global__ __launch_bounds__(256) void topk_k(float* ws) {
  __shared__ float sl[LISTCAP];
  __shared__ float rv[256];
  __shared__ int   ri[256];
  int p = blockIdx.x, tid = threadIdx.x;
  const float* glist = (const float*)((const char*)ws + OFF_LIST) + (size_t)p * LISTCAP;
  const unsigned* lcnt = (const unsigned*)((const char*)ws + OFF_LCNT);
  float* part = (float*)((char*)ws + OFF_PART);
  unsigned cnt = lcnt[p]; if (cnt > LISTCAP) cnt = LISTCAP;
  for (unsigned i = tid; i < cnt; i += 256) sl[i] = glist[i];
  __syncthreads();
  float acc = 0.f;
  for (int k = 0; k < K_TOP; ++k) {
    float mv = -1.f; int mi = LISTCAP;
    for (unsigned i = tid; i < cnt; i += 256) {
      float v = sl[i];
      if (v > mv) { mv = v; mi = (int)i; }
    }
    rv[tid] = mv; ri[tid] = mi;
    __syncthreads();
    for (int s = 128; s > 0; s >>= 1) {
      if (tid < s) {
        if (rv[tid+s] > rv[tid] || (rv[tid+s] == rv[tid] && ri[tid+s] < ri[tid])) {
          rv[tid] = rv[tid+s]; ri[tid] = ri[tid+s];
        }
      }
      __syncthreads();
    }
    if (tid == 0) {
      float best = rv[0] > 0.f ? rv[0] : 0.f;
      float sgnk = (k < 5) ? -1.f : 1.f;
      acc += sgnk * best * best;
      if (ri[0] < LISTCAP) sl[ri[0]] = -2.f;
    }
    __syncthreads();
  }
  if (tid == 0) part[p] = acc;
}

// ---------------------------------------------------------------------------
// Kernel 9: deterministic final reduction (mean over batch)
// ---------------------------------------------------------------------------
__global__ void final_k(float* ws, float* out) {
  if (threadIdx.x == 0 && blockIdx.x == 0) {
    const float* part = (const float*)((const char*)ws + OFF_PART);
    float s = 0.f;
    for (int i = 0; i < NPROB; ++i) s += part[i];
    out[0] = s / (float)NB;
  }
}

extern "C" void kernel_launch(void* const* d_in, const int* in_sizes, int n_in,
                              void* d_out, int out_size, void* d_ws, size_t ws_size,
                              hipStream_t stream) {
  const float* in = (const float*)d_in[0];
  float* ws = (float*)d_ws;
  float* out = (float*)d_out;
  hipLaunchKernelGGL(resize_init_k, dim3(RBLK + NPROB), dim3(256), 0, stream, in, ws);
  hipLaunchKernelGGL(spn_k, dim3((NPROB * NV + 255) / 256), dim3(256), 0, stream, ws);
  hipLaunchKernelGGL(chase_k, dim3((NPROB * NV + 255) / 256), dim3(256), 0, stream, ws);
  hipLaunchKernelGGL(rank_root_k, dim3(NPROB * 16), dim3(256), 0, stream, ws);
  hipLaunchKernelGGL(hash_k, dim3(NPROB * 8), dim3(256), 0, stream, ws);
  hipLaunchKernelGGL(sortcc_k, dim3(NPROB), dim3(256), 0, stream, ws);
  hipLaunchKernelGGL(kruskal_bucket_k, dim3(NPROB * KB), dim3(256), 0, stream, ws);
  hipLaunchKernelGGL(topk_k, dim3(NPROB), dim3(256), 0, stream, ws);
  hipLaunchKernelGGL(final_k, dim3(1), dim3(64), 0, stream, ws, out);
}

// Round 13
// 379.123 us; speedup vs baseline: 2.3259x; 2.3259x over previous
//
#include <hip/hip_runtime.h>
#include <math.h>

#define NB 16
#define INW 256
#define GN 100
#define NV (GN*GN)          // 10000
#define NPROB (NB*2)        // 32
#define K_TOP 20
#define HSZ 8192
#define KB 64               // positional buckets per problem
#define SNAPN 8             // snapshots (every 8 buckets)
#define RCAP 3072           // max regions per problem
#define MYCAP 128           // max edges per bucket
#define LISTCAP 3072        // max bars per problem
#define RBLK 625            // resize blocks (NB*NV/256)

// ws layout
#define OFF_RES   0               // NB*NV f32 = 640000
#define OFF_LAB   640000          // NPROB*NV u16 (spn parent)
#define OFF_DENSE 1280000         // NPROB*NV u16
#define OFF_STATE 0               // overlay: NPROB*SNAPN*RCAP u16 = 1572864 (alive only after hash)
#define OFF_ROOTV 1920000         // NPROB*RCAP u16 = 196608
#define OFF_D2B   2116608         // NPROB*RCAP f32 = 393216
#define OFF_TAB   2509824         // NPROB*HSZ u64 = 2097152 (hash table -> sorted edges)
#define OFF_ECNT  4606976         // NPROB u32
#define OFF_RCNT  4607104         // NPROB u32
#define OFF_LCNT  4607232         // NPROB u32
#define OFF_LIST  4607360         // NPROB*LISTCAP f32 = 393216
#define OFF_PART  5000576         // NPROB f32 = 128
#define OFF_FLAB  5000704         // NPROB*NV u16 = 640000 (final labels)

__device__ __forceinline__ int imin(int a, int b){ return a < b ? a : b; }
__device__ __forceinline__ int imax(int a, int b){ return a > b ? a : b; }

__device__ __forceinline__ unsigned mono32(float f){
  unsigned b = __float_as_uint(f);
  return (b & 0x80000000u) ? ~b : (b | 0x80000000u);
}
__device__ __forceinline__ float unmono(unsigned m){
  unsigned b = (m & 0x80000000u) ? (m ^ 0x80000000u) : ~m;
  return __uint_as_float(b);
}

__device__ __forceinline__ unsigned uf_find(volatile unsigned* par, unsigned x){
  unsigned p = par[x];
  while (p != x) {
    unsigned g = par[p];
    if (g != p) par[x] = g;
    x = g;
    p = par[x];
  }
  return x;
}
__device__ __forceinline__ void uf_union(volatile unsigned* vpar, unsigned* par,
                                         unsigned a, unsigned b){
  while (1) {
    unsigned ra = uf_find(vpar, a);
    unsigned rb = uf_find(vpar, b);
    if (ra == rb) break;
    unsigned lo = (ra < rb) ? ra : rb, hi = (ra < rb) ? rb : ra;
    if (atomicCAS(&par[hi], hi, lo) == hi) break;
    a = lo; b = hi;
  }
}

__device__ __forceinline__ void cub_w(int i, int& j0, float w[4]) {
  double inv = (double)INW / (double)GN;
  double sf  = ((double)i + 0.5) * inv - 0.5;
  j0 = (int)floor(sf) - 1;
  double wd[4]; double s = 0.0;
  #pragma unroll
  for (int k = 0; k < 4; ++k) {
    int j = j0 + k;
    double t = fabs(sf - (double)j);
    double v;
    if (t < 1.0)      v = ((1.5*t - 2.5)*t)*t + 1.0;
    else if (t < 2.0) v = ((-0.5*t + 2.5)*t - 4.0)*t + 2.0;
    else              v = 0.0;
    if (j < 0 || j >= INW) v = 0.0;
    wd[k] = v; s += v;
  }
  #pragma unroll
  for (int k = 0; k < 4; ++k) w[k] = (float)(wd[k] / s);
}

// ---------------------------------------------------------------------------
// Kernel 1: bicubic resize (blocks 0..624) + per-problem init (blocks 625+)
// ---------------------------------------------------------------------------
__global__ __launch_bounds__(256) void resize_init_k(const float* __restrict__ in, float* ws) {
  int tid = threadIdx.x;
  if (blockIdx.x >= RBLK) {
    int p = blockIdx.x - RBLK;
    unsigned long long* tab = (unsigned long long*)((char*)ws + OFF_TAB) + (size_t)p * HSZ;
    for (int i = tid; i < HSZ; i += 256) tab[i] = 0ull;
    if (tid == 0) {
      ((unsigned*)((char*)ws + OFF_ECNT))[p] = 0u;
      ((unsigned*)((char*)ws + OFF_RCNT))[p] = 0u;
      ((unsigned*)((char*)ws + OFF_LCNT))[p] = 0u;
    }
    return;
  }
  float* outp = (float*)((char*)ws + OFF_RES);
  int idx = blockIdx.x * 256 + tid;
  if (idx >= NB * NV) return;
  int b = idx / NV; int rem = idx - b * NV;
  int i = rem / GN; int j = rem - i * GN;
  const float* img = in + (size_t)b * INW * INW;
  int r0, c0; float wr[4], wc[4];
  cub_w(i, r0, wr);
  cub_w(j, c0, wc);
  float acc = 0.f;
  #pragma unroll
  for (int kr = 0; kr < 4; ++kr) {
    int rr = imin(imax(r0 + kr, 0), INW - 1);
    const float* row = img + rr * INW;
    int c0c = imin(imax(c0 + 0, 0), INW - 1);
    int c1c = imin(imax(c0 + 1, 0), INW - 1);
    int c2c = imin(imax(c0 + 2, 0), INW - 1);
    int c3c = imin(imax(c0 + 3, 0), INW - 1);
    float rs = wc[0]*row[c0c] + wc[1]*row[c1c] + wc[2]*row[c2c] + wc[3]*row[c3c];
    acc += wr[kr] * rs;
  }
  outp[idx] = acc;
}

// ---------------------------------------------------------------------------
// Kernel 2: steepest-earlier-neighbor (grid-wide, one thread/vertex)
// ---------------------------------------------------------------------------
__global__ __launch_bounds__(256) void spn_k(float* ws) {
  int idx = blockIdx.x * 256 + threadIdx.x;
  if (idx >= NPROB * NV) return;
  int p = idx / NV, v = idx - p * NV;
  int samp = p >> 1, neg = p & 1;
  const float* res = (const float*)((const char*)ws + OFF_RES) + samp * NV;
  unsigned short* glab = (unsigned short*)((char*)ws + OFF_LAB) + (size_t)p * NV;
  float sgn = neg ? -1.f : 1.f;
  const int nd = neg ? 4 : 6;
  int r = v / GN, c = v - r * GN;
  unsigned long long best = ((unsigned long long)mono32(sgn * res[v]) << 32) | (unsigned)~(unsigned)v;
  unsigned bi = (unsigned)v;
  bool cb[6] = { c < GN-1, c > 0, r < GN-1, r > 0,
                 (r < GN-1) && (c < GN-1), (r > 0) && (c > 0) };
  int  off[6] = { 1, -1, GN, -GN, GN+1, -(GN+1) };
  #pragma unroll
  for (int d = 0; d < 6; ++d) {
    if (d < nd && cb[d]) {
      unsigned y = (unsigned)(v + off[d]);
      unsigned long long o = ((unsigned long long)mono32(sgn * res[y]) << 32) | (unsigned)~y;
      if (o > best) { best = o; bi = y; }
    }
  }
  glab[v] = (unsigned short)bi;
}

// ---------------------------------------------------------------------------
// Kernel 3: LDS pointer-chase to root + final labels + root compaction.
// One block per problem; chase at LDS latency (~30cy/hop).
// ---------------------------------------------------------------------------
__global__ __launch_bounds__(256) void chase_lds_k(float* ws) {
  __shared__ unsigned short lab[NV];          // 20KB
  __shared__ unsigned cnt[256];
  int p = blockIdx.x, tid = threadIdx.x;
  const unsigned short* glab = (const unsigned short*)((const char*)ws + OFF_LAB) + (size_t)p * NV;
  unsigned short* flab = (unsigned short*)((char*)ws + OFF_FLAB) + (size_t)p * NV;
  unsigned short* rootv = (unsigned short*)((char*)ws + OFF_ROOTV) + (size_t)p * RCAP;
  unsigned* rcnt = (unsigned*)((char*)ws + OFF_RCNT);
  for (int i = tid; i < NV; i += 256) lab[i] = glab[i];
  __syncthreads();
  for (int v = tid; v < NV; v += 256) {
    unsigned r = lab[v];
    while (1) { unsigned n = lab[r]; if (n == r) break; r = n; }
    lab[v] = (unsigned short)r;               // compression (ancestor-safe)
    flab[v] = (unsigned short)r;
  }
  __syncthreads();
  // deterministic scan-based root compaction
  unsigned my = 0;
  for (int v = tid; v < NV; v += 256) if (lab[v] == (unsigned short)v) ++my;
  cnt[tid] = my;
  __syncthreads();
  for (int off = 1; off < 256; off <<= 1) {
    unsigned t = (tid >= off) ? cnt[tid - off] : 0u;
    __syncthreads();
    cnt[tid] += t;
    __syncthreads();
  }
  unsigned base = cnt[tid] - my;
  for (int v = tid; v < NV; v += 256) {
    if (lab[v] == (unsigned short)v) {
      if (base < RCAP) rootv[base] = (unsigned short)v;
      ++base;
    }
  }
  if (tid == 255) rcnt[p] = (cnt[255] > RCAP) ? RCAP : cnt[255];
}

// ---------------------------------------------------------------------------
// Kernel 4: rank roots desc (elder order) -> dense ids + birth table.
// 16 slices per problem; ords recomputed from rootv + res.
// ---------------------------------------------------------------------------
__global__ __launch_bounds__(256) void rank_root_k(float* ws) {
  __shared__ unsigned long long ro[RCAP];
  __shared__ unsigned short rv_sh[RCAP];
  int p = blockIdx.x / 16, sl = blockIdx.x % 16, tid = threadIdx.x;
  int samp = p >> 1, neg = p & 1;
  const float* res = (const float*)((const char*)ws + OFF_RES) + samp * NV;
  const unsigned short* rootv = (const unsigned short*)((const char*)ws + OFF_ROOTV) + (size_t)p * RCAP;
  unsigned short* dense = (unsigned short*)((char*)ws + OFF_DENSE) + (size_t)p * NV;
  float* d2b = (float*)((char*)ws + OFF_D2B) + (size_t)p * RCAP;
  const unsigned* rcnt = (const unsigned*)((const char*)ws + OFF_RCNT);
  unsigned R = rcnt[p]; if (R > RCAP) R = RCAP;
  float sgn = neg ? -1.f : 1.f;
  for (unsigned i = tid; i < R; i += 256) {
    unsigned v = rootv[i];
    ro[i] = ((unsigned long long)mono32(sgn * res[v]) << 32) | (unsigned)~v;
    rv_sh[i] = (unsigned short)v;
  }
  __syncthreads();
  unsigned RS = (R + 15) / 16;
  unsigned lo = sl * RS, hi = lo + RS; if (hi > R) hi = R;
  for (unsigned i = lo + tid; i < hi; i += 256) {
    unsigned long long oi = ro[i];
    unsigned r = 0;
    for (unsigned j = 0; j < R; ++j) r += (ro[j] > oi) ? 1u : 0u;
    dense[rv_sh[i]] = (unsigned short)r;
    d2b[r] = unmono((unsigned)(oi >> 32));
  }
}

// ---------------------------------------------------------------------------
// Kernel 5: boundary-edge dedup into GLOBAL u64 hash table. 8 slices/problem.
// ---------------------------------------------------------------------------
__global__ __launch_bounds__(256) void hash_k(float* ws) {
  int p = blockIdx.x >> 3, sl = blockIdx.x & 7, tid = threadIdx.x;
  int samp = p >> 1, neg = p & 1;
  const float* res = (const float*)((const char*)ws + OFF_RES) + samp * NV;
  const unsigned short* flab = (const unsigned short*)((const char*)ws + OFF_FLAB) + (size_t)p * NV;
  const unsigned short* gdense = (const unsigned short*)((const char*)ws + OFF_DENSE) + (size_t)p * NV;
  unsigned long long* tab = (unsigned long long*)((char*)ws + OFF_TAB) + (size_t)p * HSZ;
  float sgn = neg ? -1.f : 1.f;
  int v0 = sl * (NV / 8), v1 = v0 + (NV / 8);
  for (int v = v0 + tid; v < v1; v += 256) {
    int r = v / GN, c = v - r * GN;
    unsigned a = gdense[flab[v]];
    unsigned sv = mono32(sgn * res[v]);
    bool vb[3] = { c < GN-1, r < GN-1, (!neg) && (r < GN-1) && (c < GN-1) };
    int  vo[3] = { 1, GN, GN+1 };
    #pragma unroll
    for (int d = 0; d < 3; ++d) {
      if (vb[d]) {
        unsigned w = (unsigned)(v + vo[d]);
        unsigned b = gdense[flab[w]];
        if (a != b) {
          unsigned sw = mono32(sgn * res[w]);
          unsigned ev = (sv < sw) ? sv : sw;
          unsigned dlo = (a < b) ? a : b, dhi = (a < b) ? b : a;
          unsigned pid = (dlo << 16) | dhi;
          unsigned long long packed = ((unsigned long long)ev << 32) | pid;
          unsigned h = (pid * 2654435761u) >> 19;
          for (int t = 0; t < HSZ; ++t) {
            unsigned long long cur = tab[h];
            if (cur == 0ull) {
              unsigned long long old = atomicCAS(&tab[h], 0ull, packed);
              if (old == 0ull) break;
              cur = old;
            }
            if ((unsigned)cur == pid) { atomicMax(&tab[h], packed); break; }
            h = (h + 1) & (HSZ - 1);
          }
        }
      }
    }
  }
}

// ---------------------------------------------------------------------------
// Kernel 6: FUSED gather + in-LDS radix sort (desc by ev) + prefix-CC
// snapshots. One block/problem.
// ---------------------------------------------------------------------------
__global__ __launch_bounds__(256) void sortcc_k(float* ws) {
  __shared__ unsigned long long bufA[HSZ];    // 64KB
  __shared__ unsigned long long bufB[HSZ];    // 64KB (par after sort)
  __shared__ unsigned cnt[16 * 256];          // 16KB
  __shared__ unsigned tot[16];
  __shared__ unsigned mc_sh;
  int p = blockIdx.x, tid = threadIdx.x;
  unsigned long long* tab = (unsigned long long*)((char*)ws + OFF_TAB) + (size_t)p * HSZ;
  unsigned short* state = (unsigned short*)((char*)ws + OFF_STATE) + (size_t)p * SNAPN * RCAP;
  unsigned* ecnt = (unsigned*)((char*)ws + OFF_ECNT);
  const unsigned* rcnt = (const unsigned*)((const char*)ws + OFF_RCNT);
  unsigned R = rcnt[p]; if (R > RCAP) R = RCAP;
  if (tid == 0) mc_sh = 0;
  __syncthreads();
  for (int i = tid; i < HSZ; i += 256) {
    unsigned long long x = tab[i];
    if (x != 0ull) { unsigned k = atomicAdd(&mc_sh, 1u); bufA[k] = x; }
  }
  __syncthreads();
  unsigned E = mc_sh;
  unsigned chunk = (E + 255) >> 8;
  unsigned lo = tid * chunk; if (lo > E) lo = E;
  unsigned hi = lo + chunk; if (hi > E) hi = E;
  unsigned long long* src = bufA;
  unsigned long long* dst = bufB;
  for (int pass = 0; pass < 8; ++pass) {
    int shift = 32 + pass * 4;
    for (int d = tid; d < 16 * 256; d += 256) cnt[d] = 0;
    __syncthreads();
    for (unsigned i = lo; i < hi; ++i) {
      unsigned slot = 15u - ((unsigned)(src[i] >> shift) & 15u);
      cnt[slot * 256 + tid] += 1u;
    }
    __syncthreads();
    if (tid < 16) {
      unsigned s = 0;
      for (int t = 0; t < 256; ++t) {
        unsigned c = cnt[tid * 256 + t];
        cnt[tid * 256 + t] = s;
        s += c;
      }
      tot[tid] = s;
    }
    __syncthreads();
    if (tid == 0) {
      unsigned s = 0;
      for (int d = 0; d < 16; ++d) { unsigned c = tot[d]; tot[d] = s; s += c; }
    }
    __syncthreads();
    for (unsigned i = lo; i < hi; ++i) {
      unsigned long long x = src[i];
      unsigned slot = 15u - ((unsigned)(x >> shift) & 15u);
      unsigned off = cnt[slot * 256 + tid];
      cnt[slot * 256 + tid] = off + 1u;
      dst[tot[slot] + off] = x;
    }
    __syncthreads();
    unsigned long long* t2 = src; src = dst; dst = t2;
  }
  for (unsigned i = tid; i < E; i += 256) tab[i] = bufA[i];
  if (tid == 0) ecnt[p] = E;
  unsigned* par = (unsigned*)bufB;
  for (unsigned d = tid; d < R; d += 256) par[d] = d;
  __syncthreads();
  volatile unsigned* vpar = par;
  unsigned cp = (E + KB - 1) / KB;
  for (int s = 0; s < SNAPN; ++s) {
    for (unsigned d = tid; d < R; d += 256) {
      unsigned r = d;
      while (vpar[r] != r) r = vpar[r];
      par[d] = r;
      state[s * RCAP + d] = (unsigned short)r;
    }
    __syncthreads();
    unsigned e0 = (unsigned)s * 8u * cp; if (e0 > E) e0 = E;
    unsigned e1 = (unsigned)(s + 1) * 8u * cp; if (e1 > E) e1 = E;
    for (unsigned e = e0 + tid; e < e1; e += 256) {
      unsigned pid = (unsigned)bufA[e];
      uf_union(vpar, par, pid >> 16, pid & 0xffffu);
    }
    __syncthreads();
  }
}

// ---------------------------------------------------------------------------
// Kernel 7: bucketed Kruskal with speculative root hints.
// ---------------------------------------------------------------------------
__global__ __launch_bounds__(256) void kruskal_bucket_k(float* ws) {
  __shared__ unsigned par[RCAP];
  __shared__ unsigned hintR[MYCAP];
  __shared__ unsigned hintE[MYCAP];
  __shared__ float    hintB[MYCAP];
  __shared__ float    barbuf[MYCAP];
  __shared__ unsigned nb_sh, base_sh;
  int p = blockIdx.x / KB, bk = blockIdx.x % KB, tid = threadIdx.x;
  const unsigned long long* gedges = (const unsigned long long*)((const char*)ws + OFF_TAB) + (size_t)p * HSZ;
  const float* d2b = (const float*)((const char*)ws + OFF_D2B) + (size_t)p * RCAP;
  const unsigned short* state = (const unsigned short*)((const char*)ws + OFF_STATE) + (size_t)p * SNAPN * RCAP + (size_t)(bk >> 3) * RCAP;
  const unsigned* ecnt = (const unsigned*)((const char*)ws + OFF_ECNT);
  const unsigned* rcnt = (const unsigned*)((const char*)ws + OFF_RCNT);
  unsigned* lcnt = (unsigned*)((char*)ws + OFF_LCNT);
  float* glist = (float*)((char*)ws + OFF_LIST) + (size_t)p * LISTCAP;
  unsigned E = ecnt[p]; if (E > HSZ) E = HSZ;
  unsigned R = rcnt[p]; if (R > RCAP) R = RCAP;
  unsigned cp = (E + KB - 1) / KB;
  unsigned rep_lo = (unsigned)(bk & ~7) * cp; if (rep_lo > E) rep_lo = E;
  unsigned own_lo = (unsigned)bk * cp;        if (own_lo > E) own_lo = E;
  unsigned own_hi = own_lo + cp;              if (own_hi > E) own_hi = E;
  unsigned mc = own_hi - own_lo;
  for (unsigned d = tid; d < R; d += 256) par[d] = state[d];
  __syncthreads();
  volatile unsigned* vpar = par;
  for (unsigned e = rep_lo + tid; e < own_lo; e += 256) {
    unsigned pid = (unsigned)gedges[e];
    uf_union(vpar, par, pid >> 16, pid & 0xffffu);
  }
  __syncthreads();
  for (unsigned d = tid; d < R; d += 256) {
    unsigned r = d;
    while (vpar[r] != r) r = vpar[r];
    par[d] = r;
  }
  __syncthreads();
  if (tid < mc) {
    unsigned long long it = gedges[own_lo + tid];
    unsigned pid = (unsigned)it;
    unsigned ra = par[pid >> 16];
    unsigned rb = par[pid & 0xffffu];
    hintR[tid] = (ra << 16) | rb;
    hintE[tid] = (unsigned)(it >> 32);
    hintB[tid] = d2b[(ra > rb) ? ra : rb];
  }
  __syncthreads();
  if (tid >= 64) return;
  const int lane = tid;
  if (lane == 0) {
    unsigned nb = 0;
    for (unsigned e = 0; e < mc; ++e) {
      unsigned h = hintR[e];
      unsigned ra = h >> 16, rb = h & 0xffffu;
      if (ra == rb) continue;
      unsigned ca = ra, pa = par[ca];
      while (pa != ca) { unsigned ga = par[pa]; par[ca] = ga; ca = ga; pa = par[ca]; }
      unsigned cb = rb, pb = par[cb];
      while (pb != cb) { unsigned gb = par[pb]; par[cb] = gb; cb = gb; pb = par[cb]; }
      if (ca == cb) continue;
      unsigned win = (ca < cb) ? ca : cb;
      unsigned los = (ca < cb) ? cb : ca;
      float birth = (ca == ra && cb == rb) ? hintB[e] : d2b[los];
      barbuf[nb++] = birth - unmono(hintE[e]);
      par[los] = win;
    }
    nb_sh = nb;
  }
  __asm__ volatile("s_waitcnt lgkmcnt(0)" ::: "memory");
  __builtin_amdgcn_wave_barrier();
  if (lane == 0) base_sh = atomicAdd(&lcnt[p], nb_sh);
  __asm__ volatile("s_waitcnt vmcnt(0) lgkmcnt(0)" ::: "memory");
  __builtin_amdgcn_wave_barrier();
  unsigned nb = nb_sh, base = base_sh;
  for (unsigned i = lane; i < nb; i += 64) {
    unsigned idx = base + i;
    if (idx < LISTCAP) glist[idx] = barbuf[i];
  }
}

// ---------------------------------------------------------------------------
// Kernel 8: per-problem top-20 over compact bar list -> partial[p]
// ---------------------------------------------------------------------------
__global__ __launch_bounds__(256) void topk_k(float* ws) {
  __shared__ float sl[LISTCAP];
  __shared__ float rv[256];
  __shared__ int   ri[256];
  int p = blockIdx.x, tid = threadIdx.x;
  const float* glist = (const float*)((const char*)ws + OFF_LIST) + (size_t)p * LISTCAP;
  const unsigned* lcnt = (const unsigned*)((const char*)ws + OFF_LCNT);
  float* part = (float*)((char*)ws + OFF_PART);
  unsigned cnt = lcnt[p]; if (cnt > LISTCAP) cnt = LISTCAP;
  for (unsigned i = tid; i < cnt; i += 256) sl[i] = glist[i];
  __syncthreads();
  float acc = 0.f;
  for (int k = 0; k < K_TOP; ++k) {
    float mv = -1.f; int mi = LISTCAP;
    for (unsigned i = tid; i < cnt; i += 256) {
      float v = sl[i];
      if (v > mv) { mv = v; mi = (int)i; }
    }
    rv[tid] = mv; ri[tid] = mi;
    __syncthreads();
    for (int s = 128; s > 0; s >>= 1) {
      if (tid < s) {
        if (rv[tid+s] > rv[tid] || (rv[tid+s] == rv[tid] && ri[tid+s] < ri[tid])) {
          rv[tid] = rv[tid+s]; ri[tid] = ri[tid+s];
        }
      }
      __syncthreads();
    }
    if (tid == 0) {
      float best = rv[0] > 0.f ? rv[0] : 0.f;
      float sgnk = (k < 5) ? -1.f : 1.f;
      acc += sgnk * best * best;
      if (ri[0] < LISTCAP) sl[ri[0]] = -2.f;
    }
    __syncthreads();
  }
  if (tid == 0) part[p] = acc;
}

// ---------------------------------------------------------------------------
// Kernel 9: deterministic final reduction (mean over batch)
// ---------------------------------------------------------------------------
__global__ void final_k(float* ws, float* out) {
  if (threadIdx.x == 0 && blockIdx.x == 0) {
    const float* part = (const float*)((const char*)ws + OFF_PART);
    float s = 0.f;
    for (int i = 0; i < NPROB; ++i) s += part[i];
    out[0] = s / (float)NB;
  }
}

extern "C" void kernel_launch(void* const* d_in, const int* in_sizes, int n_in,
                              void* d_out, int out_size, void* d_ws, size_t ws_size,
                              hipStream_t stream) {
  const float* in = (const float*)d_in[0];
  float* ws = (float*)d_ws;
  float* out = (float*)d_out;
  hipLaunchKernelGGL(resize_init_k, dim3(RBLK + NPROB), dim3(256), 0, stream, in, ws);
  hipLaunchKernelGGL(spn_k, dim3((NPROB * NV + 255) / 256), dim3(256), 0, stream, ws);
  hipLaunchKernelGGL(chase_lds_k, dim3(NPROB), dim3(256), 0, stream, ws);
  hipLaunchKernelGGL(rank_root_k, dim3(NPROB * 16), dim3(256), 0, stream, ws);
  hipLaunchKernelGGL(hash_k, dim3(NPROB * 8), dim3(256), 0, stream, ws);
  hipLaunchKernelGGL(sortcc_k, dim3(NPROB), dim3(256), 0, stream, ws);
  hipLaunchKernelGGL(kruskal_bucket_k, dim3(NPROB * KB), dim3(256), 0, stream, ws);
  hipLaunchKernelGGL(topk_k, dim3(NPROB), dim3(256), 0, stream, ws);
  hipLaunchKernelGGL(final_k, dim3(1), dim3(64), 0, stream, ws, out);
}